// Round 3
// baseline (327.501 us; speedup 1.0000x reference)
//
#include <hip/hip_runtime.h>
#include <stdint.h>
#include <type_traits>

// Problem constants
#define BB  4
#define SS  2048
#define DD  1024
#define HH  16
#define HDD 64

typedef __attribute__((ext_vector_type(8))) short s16x8;   // 8 bf16 (4 VGPRs)
typedef __attribute__((ext_vector_type(4))) float f32x4;   // MFMA C/D

__device__ inline short f2bf(float f) {
    union { float f; unsigned int u; } v; v.f = f;
    unsigned int r = (v.u + 0x7fffu + ((v.u >> 16) & 1u)) >> 16; // RNE
    return (short)r;
}

#define GLL(gp, lp) __builtin_amdgcn_global_load_lds( \
    (const __attribute__((address_space(1))) void*)(gp), \
    (__attribute__((address_space(3))) void*)(lp), 16, 0, 0)

// LDS-only barrier: waits DS ops, NOT vmcnt -> register prefetch survives.
#define BAR() asm volatile("s_waitcnt lgkmcnt(0)\n\ts_barrier" ::: "memory")

// ---------------- fp32 -> bf16 cast (n % 8 == 0) ----------------
__global__ void cvt_kernel(const float* __restrict__ src, short* __restrict__ dst, int n) {
    int i = (blockIdx.x * 256 + threadIdx.x) * 8;
    if (i >= n) return;
    const float4* s = (const float4*)(src + i);
    float4 a = s[0], b = s[1];
    s16x8 o;
    o[0]=f2bf(a.x); o[1]=f2bf(a.y); o[2]=f2bf(a.z); o[3]=f2bf(a.w);
    o[4]=f2bf(b.x); o[5]=f2bf(b.y); o[6]=f2bf(b.z); o[7]=f2bf(b.w);
    *(s16x8*)(dst + i) = o;
}

// ---------------- GEMM C = A @ B^T + bias (m97 structure) ----------------
template<int EPI>
__global__ __launch_bounds__(256)
void gemm_bt(const short* __restrict__ A, const short* __restrict__ Bw,
             const float* __restrict__ bias, float* __restrict__ Cf,
             short* __restrict__ Qo, short* __restrict__ Ko, short* __restrict__ Vo,
             int M, int N, int K)
{
    __shared__ short lsA[128 * 32];
    __shared__ short lsB[128 * 32];
    const int tid  = threadIdx.x;
    const int w    = tid >> 6, lane = tid & 63;
    const int quad = lane >> 4, l15 = lane & 15;
    const int m0 = blockIdx.x * 128, n0 = blockIdx.y * 128;
    const int mw = (w & 1) * 64, nw = (w >> 1) * 64;

    f32x4 acc[4][4] = {};

    const int srow = w * 32 + (lane >> 2);
    const int scol = (lane & 3) * 8;
    const short* pA = A + (size_t)(m0 + srow) * K + scol;
    const short* pB = Bw + (size_t)(n0 + srow) * K + scol;
    short* lAbase0 = &lsA[(w * 32) * 32];
    short* lAbase1 = &lsA[(w * 32 + 16) * 32];
    short* lBbase0 = &lsB[(w * 32) * 32];
    short* lBbase1 = &lsB[(w * 32 + 16) * 32];

    for (int kk = 0; kk < K; kk += 32) {
        __syncthreads();
        GLL(pA + kk,            lAbase0);
        GLL(pA + kk + 16 * K,   lAbase1);
        GLL(pB + kk,            lBbase0);
        GLL(pB + kk + 16 * K,   lBbase1);
        asm volatile("s_waitcnt vmcnt(0)" ::: "memory");
        __syncthreads();

        s16x8 af[4], bfr[4];
        for (int t = 0; t < 4; ++t) {
            af[t]  = *(const s16x8*)&lsA[(mw + t * 16 + l15) * 32 + quad * 8];
            bfr[t] = *(const s16x8*)&lsB[(nw + t * 16 + l15) * 32 + quad * 8];
        }
        for (int i = 0; i < 4; ++i)
            for (int j = 0; j < 4; ++j)
                acc[i][j] = __builtin_amdgcn_mfma_f32_16x16x32_bf16(af[i], bfr[j], acc[i][j], 0, 0, 0);
    }

    if (EPI == 0) {
        for (int i = 0; i < 4; ++i) {
            int row = m0 + mw + i * 16 + quad * 4;
            for (int j = 0; j < 4; ++j) {
                int col = n0 + nw + j * 16 + l15;
                float bv = bias[col];
                for (int r = 0; r < 4; ++r)
                    Cf[(size_t)(row + r) * N + col] = acc[i][j][r] + bv;
            }
        }
    } else {
        for (int i = 0; i < 4; ++i) {
            int row = m0 + mw + i * 16 + quad * 4;
            for (int j = 0; j < 4; ++j) {
                int col = n0 + nw + j * 16 + l15;
                float bv = bias[col];
                int sel = col >> 10, h = (col >> 6) & 15, hd = col & 63;
                for (int r = 0; r < 4; ++r) {
                    int rr = row + r;
                    int b = rr >> 11, s = rr & 2047;
                    short val = f2bf(acc[i][j][r] + bv);
                    if (sel == 0)      Qo[(((size_t)b * HH + h) * SS + s) * HDD + hd] = val;
                    else if (sel == 1) Ko[(((size_t)b * HH + h) * SS + s) * HDD + hd] = val;
                    else               Vo[(((size_t)b * HH + h) * HDD + hd) * SS + s] = val;
                }
            }
        }
    }
}

// ---------------- causal flash attention ----------------
// Q,K: (b,h,s,hd) bf16; V: (b,h,hd,s) bf16; O: (b,s,h*64+hd) bf16
// grid (16, B*H); block handles q-tiles {31-bx, bx} (17 key-tile-units each).
// Fixed-offset softmax (scores bounded -> no online max), single l-reduction
// per q-tile. K/V register-prefetched; LDS-only raw barriers keep prefetch
// loads in flight. P aliases lsK (4 blocks/CU).
__global__ __launch_bounds__(256, 4)
void attn_kernel(const short* __restrict__ Q, const short* __restrict__ Kb,
                 const short* __restrict__ Vb, const int* __restrict__ mask,
                 short* __restrict__ O)
{
    __shared__ short lsK[128 * 72];        // [key][hd] pad 64->72; aliased by P (per-wave 16x136)
    __shared__ short lsV[64 * 136];        // [hd][key] pad 128->136
    __shared__ float lsM[128];

    const int tid  = threadIdx.x;
    const int w    = tid >> 6, lane = tid & 63;
    const int quad = lane >> 4, l15 = lane & 15;
    const int bx = blockIdx.x, bh = blockIdx.y;
    const int b = bh >> 4;
    const size_t baseQK = (size_t)bh * SS * HDD;
    const size_t baseV  = (size_t)bh * HDD * SS;
    short* lsPw = &lsK[w * 16 * 136];
    const float SC = 0.18033688f;          // (1/8) * log2(e)

    // per-thread staging coords (4 chunks of 256 threads)
    int krow[4], kcs[4], vrow[4], vcs[4];
    for (int i = 0; i < 4; ++i) {
        int ch = tid + i * 256;
        krow[i] = ch >> 3; kcs[i] = (ch & 7) * 8;
        vrow[i] = ch >> 4; vcs[i] = (ch & 15) * 8;
    }

    for (int t = 0; t < 2; ++t) {
        const int qb = t ? bx : (31 - bx);  // heavy tile first
        const int q0 = qb * 64;
        const int qrow = q0 + w * 16 + l15;
        const int rowg0 = q0 + w * 16 + quad * 4;
        const int T = (qb >> 1) + 1;        // key tiles of 128 (last is causal)

        s16x8 aq[2];
        for (int ks = 0; ks < 2; ++ks)
            aq[ks] = *(const s16x8*)(Q + baseQK + (size_t)qrow * HDD + ks * 32 + quad * 8);

        float lsum[4] = {0.f, 0.f, 0.f, 0.f};
        f32x4 o_acc[4] = {};

        // prefetch tile 0
        s16x8 kc[4], vc[4]; int mc;
        for (int i = 0; i < 4; ++i) {
            kc[i] = *(const s16x8*)(Kb + baseQK + (size_t)krow[i] * HDD + kcs[i]);
            vc[i] = *(const s16x8*)(Vb + baseV + (size_t)vrow[i] * SS + vcs[i]);
        }
        mc = (tid < 128) ? mask[b * SS + tid] : 1;

        auto tile = [&](auto CC, int kt) {
            constexpr bool CAUS = decltype(CC)::value;
            const int kv0 = kt * 128;
            BAR();                                  // prev PV/P done -> staging safe
            for (int i = 0; i < 4; ++i) {
                *(s16x8*)&lsK[krow[i] * 72 + kcs[i]]  = kc[i];
                *(s16x8*)&lsV[vrow[i] * 136 + vcs[i]] = vc[i];
            }
            if (tid < 128) lsM[tid] = mc ? 0.f : -1e30f;
            // prefetch next tile (regs free after ds_write issue)
            if (kt + 1 < T) {
                const int nk = kv0 + 128;
                for (int i = 0; i < 4; ++i) {
                    kc[i] = *(const s16x8*)(Kb + baseQK + (size_t)(nk + krow[i]) * HDD + kcs[i]);
                    vc[i] = *(const s16x8*)(Vb + baseV + (size_t)vrow[i] * SS + nk + vcs[i]);
                }
                mc = (tid < 128) ? mask[b * SS + nk + tid] : 1;
            }
            BAR();                                  // staging visible

            // S = Q K^T, exp2 immediately (fixed-offset softmax), pack to bf16
            unsigned int pk[8][2];
            for (int nt = 0; nt < 8; ++nt) {
                f32x4 s = {};
                for (int ks = 0; ks < 2; ++ks) {
                    s16x8 kf = *(const s16x8*)&lsK[(nt * 16 + l15) * 72 + ks * 32 + quad * 8];
                    s = __builtin_amdgcn_mfma_f32_16x16x32_bf16(aq[ks], kf, s, 0, 0, 0);
                }
                float madd = lsM[nt * 16 + l15];
                int colg = kv0 + nt * 16 + l15;
                float p[4];
                for (int r = 0; r < 4; ++r) {
                    float scv = s[r] * SC + madd;
                    if (CAUS && colg > rowg0 + r) scv = -1e30f;
                    p[r] = __builtin_amdgcn_exp2f(scv);
                    lsum[r] += p[r];
                }
                pk[nt][0] = (unsigned int)(unsigned short)f2bf(p[0])
                          | ((unsigned int)(unsigned short)f2bf(p[1]) << 16);
                pk[nt][1] = (unsigned int)(unsigned short)f2bf(p[2])
                          | ((unsigned int)(unsigned short)f2bf(p[3]) << 16);
            }

            BAR();                                  // all K reads done -> P may overwrite lsK
            for (int nt = 0; nt < 8; ++nt) {
                int off = nt * 16 + l15;
                lsPw[(quad * 4 + 0) * 136 + off] = (short)(pk[nt][0] & 0xffff);
                lsPw[(quad * 4 + 1) * 136 + off] = (short)(pk[nt][0] >> 16);
                lsPw[(quad * 4 + 2) * 136 + off] = (short)(pk[nt][1] & 0xffff);
                lsPw[(quad * 4 + 3) * 136 + off] = (short)(pk[nt][1] >> 16);
            }
            asm volatile("s_waitcnt lgkmcnt(0)" ::: "memory");

            // O += P V   (per-wave P region -> no barrier needed before reads)
            for (int k2 = 0; k2 < 4; ++k2) {
                s16x8 ap = *(const s16x8*)&lsPw[l15 * 136 + k2 * 32 + quad * 8];
                for (int ht = 0; ht < 4; ++ht) {
                    s16x8 vf = *(const s16x8*)&lsV[(ht * 16 + l15) * 136 + k2 * 32 + quad * 8];
                    o_acc[ht] = __builtin_amdgcn_mfma_f32_16x16x32_bf16(ap, vf, o_acc[ht], 0, 0, 0);
                }
            }
        };

        for (int kt = 0; kt < T - 1; ++kt) tile(std::false_type{}, kt);
        tile(std::true_type{}, T - 1);

        // single l-reduction per q-tile (rows live in 16-lane groups)
        const int hcol = (bh & 15) * HDD;
        for (int r = 0; r < 4; ++r) {
            float rs = lsum[r];
            rs += __shfl_xor(rs, 1);
            rs += __shfl_xor(rs, 2);
            rs += __shfl_xor(rs, 4);
            rs += __shfl_xor(rs, 8);
            float inv = 1.0f / rs;
            int srow = q0 + w * 16 + quad * 4 + r;
            size_t base = ((size_t)b * SS + srow) * DD + hcol;
            for (int ht = 0; ht < 4; ++ht)
                O[base + ht * 16 + l15] = f2bf(o_acc[ht][r] * inv);
        }
    }
}

// ---------------- launch ----------------
extern "C" void kernel_launch(void* const* d_in, const int* in_sizes, int n_in,
                              void* d_out, int out_size, void* d_ws, size_t ws_size,
                              hipStream_t stream) {
    const float* x     = (const float*)d_in[0];
    const int*   mask  = (const int*)d_in[1];
    const float* qkv_w = (const float*)d_in[2];
    const float* qkv_b = (const float*)d_in[3];
    const float* out_w = (const float*)d_in[4];
    const float* out_b = (const float*)d_in[5];
    float* out = (float*)d_out;

    const size_t M1 = (size_t)BB * SS;       // 8192
    short* ws  = (short*)d_ws;
    short* xb  = ws;
    short* qwb = xb  + M1 * DD;
    short* owb = qwb + (size_t)3 * DD * DD;
    short* Qb  = owb + (size_t)DD * DD;
    short* Kb  = Qb  + M1 * DD;
    short* Vb  = Kb  + M1 * DD;
    short* Ob  = Vb  + M1 * DD;

    cvt_kernel<<<(int)(M1 * DD / 8 / 256), 256, 0, stream>>>(x, xb, (int)(M1 * DD));
    cvt_kernel<<<3 * DD * DD / 8 / 256, 256, 0, stream>>>(qkv_w, qwb, 3 * DD * DD);
    cvt_kernel<<<DD * DD / 8 / 256, 256, 0, stream>>>(out_w, owb, DD * DD);

    gemm_bt<1><<<dim3(64, 24), 256, 0, stream>>>(xb, qwb, qkv_b, nullptr,
                                                 Qb, Kb, Vb, 8192, 3072, 1024);
    attn_kernel<<<dim3(16, BB * HH), 256, 0, stream>>>(Qb, Kb, Vb, mask, Ob);
    gemm_bt<0><<<dim3(64, 8), 256, 0, stream>>>(Ob, owb, out_b, out,
                                                nullptr, nullptr, nullptr, 8192, 1024, 1024);
}

// Round 4
// 325.029 us; speedup vs baseline: 1.0076x; 1.0076x over previous
//
#include <hip/hip_runtime.h>
#include <stdint.h>
#include <type_traits>

// Problem constants
#define BB  4
#define SS  2048
#define DD  1024
#define HH  16
#define HDD 64

typedef __attribute__((ext_vector_type(8)))  short s16x8;   // 8 bf16 (4 VGPRs)
typedef __attribute__((ext_vector_type(4)))  float f32x4;   // MFMA C/D 16x16
typedef __attribute__((ext_vector_type(16))) float f32x16;  // MFMA C/D 32x32

__device__ inline short f2bf(float f) {
    union { float f; unsigned int u; } v; v.f = f;
    unsigned int r = (v.u + 0x7fffu + ((v.u >> 16) & 1u)) >> 16; // RNE
    return (short)r;
}
__device__ inline unsigned int pack2bf(float a, float b) {
    return (unsigned int)(unsigned short)f2bf(a) | ((unsigned int)(unsigned short)f2bf(b) << 16);
}

#define GLL(gp, lp) __builtin_amdgcn_global_load_lds( \
    (const __attribute__((address_space(1))) void*)(gp), \
    (__attribute__((address_space(3))) void*)(lp), 16, 0, 0)

// ---------------- fp32 -> bf16 cast (n % 8 == 0) ----------------
__global__ void cvt_kernel(const float* __restrict__ src, short* __restrict__ dst, int n) {
    int i = (blockIdx.x * 256 + threadIdx.x) * 8;
    if (i >= n) return;
    const float4* s = (const float4*)(src + i);
    float4 a = s[0], b = s[1];
    s16x8 o;
    o[0]=f2bf(a.x); o[1]=f2bf(a.y); o[2]=f2bf(a.z); o[3]=f2bf(a.w);
    o[4]=f2bf(b.x); o[5]=f2bf(b.y); o[6]=f2bf(b.z); o[7]=f2bf(b.w);
    *(s16x8*)(dst + i) = o;
}

// ---------------- GEMM C = A @ B^T + bias (m97 structure) ----------------
template<int EPI>
__global__ __launch_bounds__(256)
void gemm_bt(const short* __restrict__ A, const short* __restrict__ Bw,
             const float* __restrict__ bias, float* __restrict__ Cf,
             short* __restrict__ Qo, short* __restrict__ Ko, short* __restrict__ Vo,
             int M, int N, int K)
{
    __shared__ short lsA[128 * 32];
    __shared__ short lsB[128 * 32];
    const int tid  = threadIdx.x;
    const int w    = tid >> 6, lane = tid & 63;
    const int quad = lane >> 4, l15 = lane & 15;
    const int m0 = blockIdx.x * 128, n0 = blockIdx.y * 128;
    const int mw = (w & 1) * 64, nw = (w >> 1) * 64;

    f32x4 acc[4][4] = {};

    const int srow = w * 32 + (lane >> 2);
    const int scol = (lane & 3) * 8;
    const short* pA = A + (size_t)(m0 + srow) * K + scol;
    const short* pB = Bw + (size_t)(n0 + srow) * K + scol;
    short* lAbase0 = &lsA[(w * 32) * 32];
    short* lAbase1 = &lsA[(w * 32 + 16) * 32];
    short* lBbase0 = &lsB[(w * 32) * 32];
    short* lBbase1 = &lsB[(w * 32 + 16) * 32];

    for (int kk = 0; kk < K; kk += 32) {
        __syncthreads();
        GLL(pA + kk,            lAbase0);
        GLL(pA + kk + 16 * K,   lAbase1);
        GLL(pB + kk,            lBbase0);
        GLL(pB + kk + 16 * K,   lBbase1);
        asm volatile("s_waitcnt vmcnt(0)" ::: "memory");
        __syncthreads();

        s16x8 af[4], bfr[4];
        for (int t = 0; t < 4; ++t) {
            af[t]  = *(const s16x8*)&lsA[(mw + t * 16 + l15) * 32 + quad * 8];
            bfr[t] = *(const s16x8*)&lsB[(nw + t * 16 + l15) * 32 + quad * 8];
        }
        for (int i = 0; i < 4; ++i)
            for (int j = 0; j < 4; ++j)
                acc[i][j] = __builtin_amdgcn_mfma_f32_16x16x32_bf16(af[i], bfr[j], acc[i][j], 0, 0, 0);
    }

    if (EPI == 0) {
        for (int i = 0; i < 4; ++i) {
            int row = m0 + mw + i * 16 + quad * 4;
            for (int j = 0; j < 4; ++j) {
                int col = n0 + nw + j * 16 + l15;
                float bv = bias[col];
                for (int r = 0; r < 4; ++r)
                    Cf[(size_t)(row + r) * N + col] = acc[i][j][r] + bv;
            }
        }
    } else {
        for (int i = 0; i < 4; ++i) {
            int row = m0 + mw + i * 16 + quad * 4;
            for (int j = 0; j < 4; ++j) {
                int col = n0 + nw + j * 16 + l15;
                float bv = bias[col];
                int sel = col >> 10, h = (col >> 6) & 15, hd = col & 63;
                for (int r = 0; r < 4; ++r) {
                    int rr = row + r;
                    int b = rr >> 11, s = rr & 2047;
                    short val = f2bf(acc[i][j][r] + bv);
                    if (sel == 0)      Qo[(((size_t)b * HH + h) * SS + s) * HDD + hd] = val;
                    else if (sel == 1) Ko[(((size_t)b * HH + h) * SS + s) * HDD + hd] = val;
                    else               Vo[(((size_t)b * HH + h) * HDD + hd) * SS + s] = val;
                }
            }
        }
    }
}

// ---------------- causal flash attention, 32x32 MFMA, S^T form ----------------
// Q,K: (b,h,s,hd) bf16; V: (b,h,hd,s) bf16; O: (b,s,h*64+hd) bf16
// grid (8, B*H); block = 128 q-rows; q-tile pair {15-bx, bx} (17 key-tile units each).
// S^T = K·Q^T so q lives in lane&31: lsum is in-lane; P(C-layout) -> PV B-frag via
// one half-wave shfl_xor(32) exchange (no LDS roundtrip). K/V staged by
// global_load_lds into XOR-swizzled chunk layouts (K reads 4-way, V reads 2-way).
__global__ __launch_bounds__(256, 4)
void attn_kernel(const short* __restrict__ Q, const short* __restrict__ Kb,
                 const short* __restrict__ Vb, const int* __restrict__ mask,
                 short* __restrict__ O)
{
    __shared__ short lsK[128 * 64];   // chunk p=key*8+(cc^(key&7)) holds K[kv0+key][cc*8..+7]
    __shared__ short lsV[64 * 128];   // chunk p=hd*16+(cc^(hd&15)) holds V^T[hd][kv0+cc*8..+7]
    __shared__ float lsM[128];        // additive key mask

    const int tid = threadIdx.x;
    const int w   = tid >> 6, lane = tid & 63;
    const int h   = lane >> 5, q = lane & 31;     // half-wave, q-column
    const int bx = blockIdx.x, bh = blockIdx.y;
    const int b = bh >> 4;
    const size_t baseQK = (size_t)bh * SS * HDD;
    const size_t baseV  = (size_t)bh * HDD * SS;
    const float SC = 0.18033688f;                 // (1/8) * log2(e)

    for (int t = 0; t < 2; ++t) {
        const int qb = t ? bx : (15 - bx);        // heavy q-tile first
        const int q0 = qb * 128;
        const int s_row = q0 + w * 32 + q;        // this lane's q row
        const int T = qb + 1;

        // Q fragments (B-frag: n=lane&31=q, k=hd=kb*16+h*8+j)
        s16x8 bq[4];
        for (int kb = 0; kb < 4; ++kb)
            bq[kb] = *(const s16x8*)(Q + baseQK + (size_t)s_row * HDD + kb * 16 + h * 8);

        float lsum = 0.f;
        f32x16 oa[2] = {};                        // O^T accs: mt = hd-half

        auto tile = [&](auto CC, int kt) {
            constexpr bool CAUS = decltype(CC)::value;
            const int kv0 = kt * 128;
            __syncthreads();                      // prev tile's LDS reads done
            // stage K,V via global_load_lds (wave-uniform base + lane*16)
            for (int i = 0; i < 4; ++i) {
                const int p0 = w * 256 + i * 64;  // uniform chunk base
                const int p  = p0 + lane;
                const int key = p >> 3, cck = (p & 7) ^ (key & 7);
                GLL(Kb + baseQK + (size_t)(kv0 + key) * HDD + cck * 8, &lsK[p0 * 8]);
                const int hd = p >> 4, ccv = (p & 15) ^ (hd & 15);
                GLL(Vb + baseV + (size_t)hd * SS + kv0 + ccv * 8, &lsV[p0 * 8]);
            }
            if (tid < 32) {
                int4 mv = *(const int4*)(mask + b * SS + kv0 + tid * 4);
                float4 f;
                f.x = mv.x ? 0.f : -1e30f; f.y = mv.y ? 0.f : -1e30f;
                f.z = mv.z ? 0.f : -1e30f; f.w = mv.w ? 0.f : -1e30f;
                *(float4*)&lsM[tid * 4] = f;
            }
            __syncthreads();                      // drains vmcnt for GLL too

            for (int nt = 0; nt < 4; ++nt) {
                // S^T acc: rows = keys nt*32 + (reg&3)+8*(reg>>2)+4h, col = q
                f32x16 sa = {};
                for (int kb = 0; kb < 4; ++kb) {
                    const int key = nt * 32 + q;                 // A m=lane&31
                    const int cc  = (kb * 2 + h) ^ (key & 7);
                    s16x8 ak = *(const s16x8*)&lsK[(key * 8 + cc) * 8];
                    sa = __builtin_amdgcn_mfma_f32_32x32x16_bf16(ak, bq[kb], sa, 0, 0, 0);
                }
                // scale + mask + exp2 + pack to bf16 pairs
                unsigned int pk2[4][2];
                for (int g = 0; g < 4; ++g) {
                    float4 mq = *(const float4*)&lsM[nt * 32 + 8 * g + 4 * h];
                    float pv[4];
                    for (int r = 0; r < 4; ++r) {
                        float v = sa[g * 4 + r] * SC + ((const float*)&mq)[r];
                        if (CAUS) {
                            int key_l = nt * 32 + r + 8 * g + 4 * h;
                            if (key_l > w * 32 + q) v = -1e30f;
                        }
                        float p = __builtin_amdgcn_exp2f(v);
                        pv[r] = p;
                        lsum += p;
                    }
                    pk2[g][0] = pack2bf(pv[0], pv[1]);
                    pk2[g][1] = pack2bf(pv[2], pv[3]);
                }
                // O^T += V^T · P^T : B-frag of P via half-wave exchange
                for (int kb2 = 0; kb2 < 2; ++kb2) {
                    // h=0 owns g=2kb2 (keys +0..3), needs partner g=2kb2 (keys +4..7)
                    // h=1 owns g=2kb2+1 (keys +12..15), needs partner g=2kb2+1 (keys +8..11)
                    const int g_own = 2 * kb2 + h;
                    unsigned int s0 = h ? pk2[2 * kb2][0] : pk2[2 * kb2 + 1][0];
                    unsigned int s1 = h ? pk2[2 * kb2][1] : pk2[2 * kb2 + 1][1];
                    unsigned int r0 = (unsigned int)__shfl_xor((int)s0, 32);
                    unsigned int r1 = (unsigned int)__shfl_xor((int)s1, 32);
                    union { s16x8 v; unsigned int d[4]; } bp;
                    if (h == 0) { bp.d[0] = pk2[g_own][0]; bp.d[1] = pk2[g_own][1]; bp.d[2] = r0; bp.d[3] = r1; }
                    else        { bp.d[0] = r0; bp.d[1] = r1; bp.d[2] = pk2[g_own][0]; bp.d[3] = pk2[g_own][1]; }
                    for (int mt = 0; mt < 2; ++mt) {
                        const int hd = mt * 32 + q;              // A m=lane&31
                        const int cc = ((nt * 2 + kb2) * 2 + h) ^ (hd & 15);
                        s16x8 av = *(const s16x8*)&lsV[(hd * 16 + cc) * 8];
                        oa[mt] = __builtin_amdgcn_mfma_f32_32x32x16_bf16(av, bp.v, oa[mt], 0, 0, 0);
                    }
                }
            }
        };

        for (int kt = 0; kt < T - 1; ++kt) tile(std::false_type{}, kt);
        tile(std::true_type{}, T - 1);

        // epilogue: normalize, O^T regs -> O (b, s, head*64+hd) bf16, b64 stores
        float ls2 = lsum + __shfl_xor(lsum, 32);
        float inv = 1.0f / ls2;
        const int hcol = (bh & 15) * HDD;
        const size_t obase = ((size_t)b * SS + s_row) * DD + hcol;
        for (int mt = 0; mt < 2; ++mt) {
            for (int g = 0; g < 4; ++g) {
                const int hd0 = mt * 32 + 8 * g + 4 * h;
                unsigned int lo = pack2bf(oa[mt][g * 4 + 0] * inv, oa[mt][g * 4 + 1] * inv);
                unsigned int hi = pack2bf(oa[mt][g * 4 + 2] * inv, oa[mt][g * 4 + 3] * inv);
                uint2 st; st.x = lo; st.y = hi;
                *(uint2*)&O[obase + hd0] = st;
            }
        }
    }
}

// ---------------- launch ----------------
extern "C" void kernel_launch(void* const* d_in, const int* in_sizes, int n_in,
                              void* d_out, int out_size, void* d_ws, size_t ws_size,
                              hipStream_t stream) {
    const float* x     = (const float*)d_in[0];
    const int*   mask  = (const int*)d_in[1];
    const float* qkv_w = (const float*)d_in[2];
    const float* qkv_b = (const float*)d_in[3];
    const float* out_w = (const float*)d_in[4];
    const float* out_b = (const float*)d_in[5];
    float* out = (float*)d_out;

    const size_t M1 = (size_t)BB * SS;       // 8192
    short* ws  = (short*)d_ws;
    short* xb  = ws;
    short* qwb = xb  + M1 * DD;
    short* owb = qwb + (size_t)3 * DD * DD;
    short* Qb  = owb + (size_t)DD * DD;
    short* Kb  = Qb  + M1 * DD;
    short* Vb  = Kb  + M1 * DD;
    short* Ob  = Vb  + M1 * DD;

    cvt_kernel<<<(int)(M1 * DD / 8 / 256), 256, 0, stream>>>(x, xb, (int)(M1 * DD));
    cvt_kernel<<<3 * DD * DD / 8 / 256, 256, 0, stream>>>(qkv_w, qwb, 3 * DD * DD);
    cvt_kernel<<<DD * DD / 8 / 256, 256, 0, stream>>>(out_w, owb, DD * DD);

    gemm_bt<1><<<dim3(64, 24), 256, 0, stream>>>(xb, qwb, qkv_b, nullptr,
                                                 Qb, Kb, Vb, 8192, 3072, 1024);
    attn_kernel<<<dim3(8, BB * HH), 256, 0, stream>>>(Qb, Kb, Vb, mask, Ob);
    gemm_bt<0><<<dim3(64, 8), 256, 0, stream>>>(Ob, owb, out_b, out,
                                                nullptr, nullptr, nullptr, 8192, 1024, 1024);
}